// Round 6
// baseline (18648.401 us; speedup 1.0000x reference)
//
#include <hip/hip_runtime.h>
#include <math.h>

typedef _Float16 f16;
typedef _Float16 f16x8 __attribute__((ext_vector_type(8)));
typedef float f32x4 __attribute__((ext_vector_type(4)));
typedef unsigned long long u64;

#define NWG 160
#define CG 20  // col groups per row group (16 h + 4 y)

// ---------------- prep kernels ----------------

// traj[0] = x0 (fp32), x0 split into hi/lo f16; block 0 zeroes the sync area
__global__ __launch_bounds__(256) void prep_copy_x0(const float* __restrict__ x0,
                                                    float* __restrict__ traj,
                                                    f16* __restrict__ xhi,
                                                    f16* __restrict__ xlo,
                                                    unsigned* __restrict__ syncarea) {
    if (blockIdx.x == 0) {
        #pragma unroll
        for (int j = 0; j < 4; ++j) syncarea[threadIdx.x * 4 + j] = 0u;
    }
    int i = blockIdx.x * 256 + threadIdx.x;  // 65536 total
    float v = x0[i];
    traj[i] = v;
    f16 h = (f16)v;
    xhi[i] = h;
    xlo[i] = (f16)(v - (float)h);
}

__global__ __launch_bounds__(256) void prep_cast2(const float* __restrict__ src,
                                                  f16* __restrict__ hi,
                                                  f16* __restrict__ lo) {
    int i = blockIdx.x * 256 + threadIdx.x;
    float v = src[i];
    f16 h = (f16)v;
    hi[i] = h;
    lo[i] = (f16)(v - (float)h);
}

__global__ __launch_bounds__(256) void prep_bias(const float* __restrict__ bih,
                                                 const float* __restrict__ bhh,
                                                 const float* __restrict__ bfc,
                                                 const float* __restrict__ Wih,
                                                 float* __restrict__ b1,
                                                 float* __restrict__ bcmb) {
    int wave = blockIdx.x * 4 + (threadIdx.x >> 6);  // 64 waves total
    int lane = threadIdx.x & 63;
    for (int j = wave * 16; j < wave * 16 + 16; ++j) {
        float s = 0.f;
        for (int o = lane; o < 256; o += 64) s += bfc[o] * Wih[j * 256 + o];
        for (int off = 32; off; off >>= 1) s += __shfl_down(s, off);
        if (lane == 0) {
            float t = bih[j] + bhh[j];
            b1[j] = t;
            bcmb[j] = t + s;
        }
    }
}

// Bt[j][k] = W_hh[j][k] + sum_o W_ih[j][o] * W_fc[o][k]  (fp32), split hi/lo
__global__ __launch_bounds__(256) void prep_wcmb(const float* __restrict__ Wih,
                                                 const float* __restrict__ Wfc,
                                                 const float* __restrict__ Whh,
                                                 f16* __restrict__ Bt_hi,
                                                 f16* __restrict__ Bt_lo) {
    __shared__ float As[64][65];
    __shared__ float Bs[64][65];
    int j0 = blockIdx.y * 64, k0 = blockIdx.x * 64;
    int tid = threadIdx.x;
    float acc[4][4] = {};
    for (int o0 = 0; o0 < 256; o0 += 64) {
        __syncthreads();
        #pragma unroll
        for (int i = 0; i < 16; ++i) {
            int e = i * 256 + tid;
            int r = e >> 6, c = e & 63;
            As[r][c] = Wih[(j0 + r) * 256 + o0 + c];
            Bs[r][c] = Wfc[(o0 + r) * 1024 + k0 + c];
        }
        __syncthreads();
        int ty = tid >> 4, tx = tid & 15;
        for (int o = 0; o < 64; ++o) {
            float a[4], b[4];
            #pragma unroll
            for (int i = 0; i < 4; ++i) a[i] = As[ty * 4 + i][o];
            #pragma unroll
            for (int i = 0; i < 4; ++i) b[i] = Bs[o][tx * 4 + i];
            #pragma unroll
            for (int i = 0; i < 4; ++i)
                #pragma unroll
                for (int jj = 0; jj < 4; ++jj) acc[i][jj] += a[i] * b[jj];
        }
    }
    int ty = tid >> 4, tx = tid & 15;
    #pragma unroll
    for (int i = 0; i < 4; ++i)
        #pragma unroll
        for (int jj = 0; jj < 4; ++jj) {
            int j = j0 + ty * 4 + i, k = k0 + tx * 4 + jj;
            float v = acc[i][jj] + Whh[j * 1024 + k];
            f16 h = (f16)v;
            Bt_hi[j * 1024 + k] = h;
            Bt_lo[j * 1024 + k] = (f16)(v - (float)h);
        }
}

// ---------------- persistent rollout kernel ----------------

// Agent-scope (cache-bypassing, cross-XCD-coherent) 16B load / 2B store for h.
union v16u { u64 q[2]; f16x8 v; };
__device__ __forceinline__ f16x8 ld_agent16(const f16* p) {
    v16u u;
    u.q[0] = __hip_atomic_load((const u64*)p, __ATOMIC_RELAXED, __HIP_MEMORY_SCOPE_AGENT);
    u.q[1] = __hip_atomic_load((const u64*)p + 1, __ATOMIC_RELAXED, __HIP_MEMORY_SCOPE_AGENT);
    return u.v;
}
__device__ __forceinline__ void st_agent_f16(f16* p, f16 v) {
    __hip_atomic_store((unsigned short*)p, __builtin_bit_cast(unsigned short, v),
                       __ATOMIC_RELAXED, __HIP_MEMORY_SCOPE_AGENT);
}

// Placement-independent barrier: __syncthreads drains vmcnt (agent stores have
// reached the coherence point), then one agent-scope arrive + relaxed spin.
// No fences / cache maintenance needed: all cross-WG data moves via
// cache-bypassing agent-scope ops; everything else is read-only or private.
// Bounded spin: on (never-expected) stall, give up instead of hanging the GPU.
__device__ __forceinline__ void group_barrier(unsigned* cnt, unsigned target,
                                              bool& gaveup) {
    __syncthreads();
    if (threadIdx.x == 0 && !gaveup) {
        __hip_atomic_fetch_add(cnt, 1u, __ATOMIC_RELAXED, __HIP_MEMORY_SCOPE_AGENT);
        int iters = 0;
        while (__hip_atomic_load(cnt, __ATOMIC_RELAXED, __HIP_MEMORY_SCOPE_AGENT) < target) {
            __builtin_amdgcn_s_sleep(1);
            if (++iters > (1 << 22)) { gaveup = true; break; }
        }
    }
    __syncthreads();
}

__global__ __launch_bounds__(512, 1) void rollout(
    const f16* __restrict__ x0_hi, const f16* __restrict__ x0_lo,
    const f16* __restrict__ Wih_hi, const f16* __restrict__ Wih_lo,
    const f16* __restrict__ Bt_hi, const f16* __restrict__ Bt_lo,
    const float* __restrict__ b1, const float* __restrict__ bcmb,
    const float* __restrict__ bfc,
    f16* __restrict__ h_hi0, f16* __restrict__ h_lo0,
    f16* __restrict__ h_hi1, f16* __restrict__ h_lo1,
    float* __restrict__ traj, unsigned* __restrict__ syncarea) {
    __shared__ f16 Bs[64 * 1024];  // 128 KB: B_hi slice (64 cols x K=1024), swizzled

    int wg = blockIdx.x;
    int g = wg & 7;    // row group (pure index partition — no placement assumption)
    int cg = wg >> 3;  // col group 0..19 (0..15 h, 16..19 y)
    int tid = threadIdx.x;
    int lane = tid & 63;
    int wid = tid >> 6;   // 0..7
    int mf = wid & 1;     // M fragment (2 x 16 rows)
    int nf = wid >> 1;    // N fragment (4 x 16 cols)
    int l15 = lane & 15;
    int klo = (lane >> 4) * 8;

    bool is_h = (cg < 16);
    int colbase = is_h ? cg * 64 : 1024 + (cg - 16) * 64;
    int cl = nf * 16 + l15;        // local col 0..63
    int colg = colbase + cl;       // global col in Bt (0..1279)
    int arow = g * 32 + mf * 16 + l15;
    int orow = g * 32 + mf * 16 + (lane >> 4) * 4;

    unsigned* cnt = syncarea + g * 64;  // per-group counter, 256B spacing, prep-zeroed
    bool gaveup = false;

    // ---- stage B_hi slice to LDS (XOR-swizzled) ----
    {
        const char* gsrc = (const char*)(Bt_hi + (size_t)colbase * 1024);
        char* bs = (char*)Bs;
        #pragma unroll
        for (int i = 0; i < 16; ++i) {
            int f = (tid + i * 512) * 16;  // 0 .. 131072
            int c = f >> 11;
            f16x8 v = *(const f16x8*)(gsrc + f);
            *(f16x8*)(bs + (f ^ ((c & 7) << 4))) = v;
        }
    }

    // ---- step 1: h_1 = tanh(x0 @ Wih^T + b_ih + b_hh) -> buf1 (h-WGs only) ----
    if (is_h) {
        const f16* a_h = x0_hi + arow * 256 + klo;
        const f16* a_l = x0_lo + arow * 256 + klo;
        const f16* b_h = Wih_hi + (size_t)colg * 256 + klo;
        const f16* b_lp = Wih_lo + (size_t)colg * 256 + klo;
        f32x4 acc = {0.f, 0.f, 0.f, 0.f};
        #pragma unroll
        for (int kk = 0; kk < 256; kk += 32) {
            f16x8 ah = *(const f16x8*)(a_h + kk);
            f16x8 al = *(const f16x8*)(a_l + kk);
            f16x8 bh = *(const f16x8*)(b_h + kk);
            f16x8 bl = *(const f16x8*)(b_lp + kk);
            acc = __builtin_amdgcn_mfma_f32_16x16x32_f16(ah, bh, acc, 0, 0, 0);
            acc = __builtin_amdgcn_mfma_f32_16x16x32_f16(ah, bl, acc, 0, 0, 0);
            acc = __builtin_amdgcn_mfma_f32_16x16x32_f16(al, bh, acc, 0, 0, 0);
        }
        float bias1 = b1[colg];
        #pragma unroll
        for (int r = 0; r < 4; ++r) {
            float t = tanhf(acc[r] + bias1);
            f16 th = (f16)t;
            st_agent_f16(&h_hi1[(orow + r) * 1024 + colg], th);
            st_agent_f16(&h_lo1[(orow + r) * 1024 + colg], (f16)(t - (float)th));
        }
    }
    group_barrier(cnt, 1u * CG, gaveup);

    // ---- main loop: iteration t computes h_t (h-WGs) and y_{t-1} (y-WGs) ----
    const char* bs = (const char*)Bs;
    const f16* b_l_base = Bt_lo + (size_t)colg * 1024 + klo;
    float bias_c = is_h ? bcmb[colg] : bfc[colg - 1024];
    int swz = (cl & 7) << 4;
    int bo0 = cl * 2048 + klo * 2;

    for (int t = 2; t <= 511; ++t) {
        const f16* src_h = ((t - 1) & 1) ? h_hi1 : h_hi0;
        const f16* src_l = ((t - 1) & 1) ? h_lo1 : h_lo0;
        const f16* a_h = src_h + (size_t)arow * 1024 + klo;
        const f16* a_l = src_l + (size_t)arow * 1024 + klo;
        f32x4 acc = {0.f, 0.f, 0.f, 0.f};
        #pragma unroll 4
        for (int kk = 0; kk < 1024; kk += 32) {
            f16x8 ah = ld_agent16(a_h + kk);
            f16x8 al = ld_agent16(a_l + kk);
            f16x8 bh = *(const f16x8*)(bs + ((bo0 + kk * 2) ^ swz));
            f16x8 bl = *(const f16x8*)(b_l_base + kk);
            acc = __builtin_amdgcn_mfma_f32_16x16x32_f16(ah, bh, acc, 0, 0, 0);
            acc = __builtin_amdgcn_mfma_f32_16x16x32_f16(ah, bl, acc, 0, 0, 0);
            acc = __builtin_amdgcn_mfma_f32_16x16x32_f16(al, bh, acc, 0, 0, 0);
        }
        if (is_h) {
            f16* dh = (t & 1) ? h_hi1 : h_hi0;
            f16* dl = (t & 1) ? h_lo1 : h_lo0;
            #pragma unroll
            for (int r = 0; r < 4; ++r) {
                float v = tanhf(acc[r] + bias_c);
                f16 th = (f16)v;
                st_agent_f16(&dh[(orow + r) * 1024 + colg], th);
                st_agent_f16(&dl[(orow + r) * 1024 + colg], (f16)(v - (float)th));
            }
        } else {
            float* y = traj + (size_t)(t - 1) * 65536;
            #pragma unroll
            for (int r = 0; r < 4; ++r)
                y[(orow + r) * 256 + (colg - 1024)] = acc[r] + bias_c;
        }
        group_barrier(cnt, (unsigned)t * CG, gaveup);
    }

    // ---- final: y_511 from h_511 (buf1) ----
    if (!is_h) {
        const f16* a_h = h_hi1 + (size_t)arow * 1024 + klo;
        const f16* a_l = h_lo1 + (size_t)arow * 1024 + klo;
        f32x4 acc = {0.f, 0.f, 0.f, 0.f};
        #pragma unroll 4
        for (int kk = 0; kk < 1024; kk += 32) {
            f16x8 ah = ld_agent16(a_h + kk);
            f16x8 al = ld_agent16(a_l + kk);
            f16x8 bh = *(const f16x8*)(bs + ((bo0 + kk * 2) ^ swz));
            f16x8 bl = *(const f16x8*)(b_l_base + kk);
            acc = __builtin_amdgcn_mfma_f32_16x16x32_f16(ah, bh, acc, 0, 0, 0);
            acc = __builtin_amdgcn_mfma_f32_16x16x32_f16(ah, bl, acc, 0, 0, 0);
            acc = __builtin_amdgcn_mfma_f32_16x16x32_f16(al, bh, acc, 0, 0, 0);
        }
        float* y = traj + (size_t)511 * 65536;
        #pragma unroll
        for (int r = 0; r < 4; ++r)
            y[(orow + r) * 256 + (colg - 1024)] = acc[r] + bias_c;
    }
}

// ---------------- launch ----------------

extern "C" void kernel_launch(void* const* d_in, const int* in_sizes, int n_in,
                              void* d_out, int out_size, void* d_ws, size_t ws_size,
                              hipStream_t stream) {
    const float* x0 = (const float*)d_in[0];
    const float* Wih = (const float*)d_in[1];
    const float* bih = (const float*)d_in[2];
    const float* Whh = (const float*)d_in[3];
    const float* bhh = (const float*)d_in[4];
    const float* Wfc = (const float*)d_in[5];
    const float* bfc = (const float*)d_in[6];
    float* traj = (float*)d_out;  // [512][256][256]

    char* w = (char*)d_ws;
    size_t off = 0;
    f16* Bt_hi = (f16*)(w + off); off += 1280u * 1024 * 2;
    f16* Bt_lo = (f16*)(w + off); off += 1280u * 1024 * 2;
    f16* Wih_hi = (f16*)(w + off); off += 1024u * 256 * 2;
    f16* Wih_lo = (f16*)(w + off); off += 1024u * 256 * 2;
    f16* x0_hi = (f16*)(w + off); off += 256u * 256 * 2;
    f16* x0_lo = (f16*)(w + off); off += 256u * 256 * 2;
    f16* h_hi0 = (f16*)(w + off); off += 256u * 1024 * 2;
    f16* h_lo0 = (f16*)(w + off); off += 256u * 1024 * 2;
    f16* h_hi1 = (f16*)(w + off); off += 256u * 1024 * 2;
    f16* h_lo1 = (f16*)(w + off); off += 256u * 1024 * 2;
    float* b1 = (float*)(w + off); off += 4096;
    float* bcmb = (float*)(w + off); off += 4096;
    unsigned* syncarea = (unsigned*)(w + off); off += 4096;

    // prep (zeroes sync area every launch -> graph-replay safe)
    prep_copy_x0<<<dim3(256), dim3(256), 0, stream>>>(x0, traj, x0_hi, x0_lo, syncarea);
    prep_cast2<<<dim3(1024), dim3(256), 0, stream>>>(Wih, Wih_hi, Wih_lo);
    prep_bias<<<dim3(16), dim3(256), 0, stream>>>(bih, bhh, bfc, Wih, b1, bcmb);
    prep_cast2<<<dim3(1024), dim3(256), 0, stream>>>(Wfc, Bt_hi + 1024 * 1024,
                                                     Bt_lo + 1024 * 1024);
    prep_wcmb<<<dim3(16, 16), dim3(256), 0, stream>>>(Wih, Wfc, Whh, Bt_hi, Bt_lo);

    // persistent rollout: 160 WGs x 512 threads, 1 WG/CU (128 KB LDS).
    // Cross-WG h exchange is agent-scope (coherence-point) only -> correct for
    // ANY workgroup->XCD placement; barrier does zero cache maintenance.
    rollout<<<dim3(NWG), dim3(512), 0, stream>>>(
        x0_hi, x0_lo, Wih_hi, Wih_lo, Bt_hi, Bt_lo, b1, bcmb, bfc,
        h_hi0, h_lo0, h_hi1, h_lo1, traj, syncarea);
}

// Round 7
// 14932.504 us; speedup vs baseline: 1.2488x; 1.2488x over previous
//
#include <hip/hip_runtime.h>
#include <math.h>

typedef _Float16 f16;
typedef _Float16 f16x8 __attribute__((ext_vector_type(8)));
typedef float f32x4 __attribute__((ext_vector_type(4)));
typedef unsigned long long u64;
typedef unsigned short u16;

#define NWG 160
#define MFMA16 __builtin_amdgcn_mfma_f32_16x16x32_f16

// ---------------- prep kernels ----------------

__global__ __launch_bounds__(256) void prep_copy_x0(const float* __restrict__ x0,
                                                    float* __restrict__ traj,
                                                    f16* __restrict__ xhi,
                                                    f16* __restrict__ xlo,
                                                    unsigned* __restrict__ syncarea) {
    if (blockIdx.x == 0) {
        #pragma unroll
        for (int j = 0; j < 4; ++j) syncarea[threadIdx.x * 4 + j] = 0u;
    }
    int i = blockIdx.x * 256 + threadIdx.x;  // 65536 total
    float v = x0[i];
    traj[i] = v;
    f16 h = (f16)v;
    xhi[i] = h;
    xlo[i] = (f16)(v - (float)h);
}

__global__ __launch_bounds__(256) void prep_cast2(const float* __restrict__ src,
                                                  f16* __restrict__ hi,
                                                  f16* __restrict__ lo) {
    int i = blockIdx.x * 256 + threadIdx.x;
    float v = src[i];
    f16 h = (f16)v;
    hi[i] = h;
    lo[i] = (f16)(v - (float)h);
}

__global__ __launch_bounds__(256) void prep_bias(const float* __restrict__ bih,
                                                 const float* __restrict__ bhh,
                                                 const float* __restrict__ bfc,
                                                 const float* __restrict__ Wih,
                                                 float* __restrict__ b1,
                                                 float* __restrict__ bcmb) {
    int wave = blockIdx.x * 4 + (threadIdx.x >> 6);  // 64 waves total
    int lane = threadIdx.x & 63;
    for (int j = wave * 16; j < wave * 16 + 16; ++j) {
        float s = 0.f;
        for (int o = lane; o < 256; o += 64) s += bfc[o] * Wih[j * 256 + o];
        for (int off = 32; off; off >>= 1) s += __shfl_down(s, off);
        if (lane == 0) {
            float t = bih[j] + bhh[j];
            b1[j] = t;
            bcmb[j] = t + s;
        }
    }
}

__global__ __launch_bounds__(256) void prep_wcmb(const float* __restrict__ Wih,
                                                 const float* __restrict__ Wfc,
                                                 const float* __restrict__ Whh,
                                                 f16* __restrict__ Bt_hi,
                                                 f16* __restrict__ Bt_lo) {
    __shared__ float As[64][65];
    __shared__ float Bs[64][65];
    int j0 = blockIdx.y * 64, k0 = blockIdx.x * 64;
    int tid = threadIdx.x;
    float acc[4][4] = {};
    for (int o0 = 0; o0 < 256; o0 += 64) {
        __syncthreads();
        #pragma unroll
        for (int i = 0; i < 16; ++i) {
            int e = i * 256 + tid;
            int r = e >> 6, c = e & 63;
            As[r][c] = Wih[(j0 + r) * 256 + o0 + c];
            Bs[r][c] = Wfc[(o0 + r) * 1024 + k0 + c];
        }
        __syncthreads();
        int ty = tid >> 4, tx = tid & 15;
        for (int o = 0; o < 64; ++o) {
            float a[4], b[4];
            #pragma unroll
            for (int i = 0; i < 4; ++i) a[i] = As[ty * 4 + i][o];
            #pragma unroll
            for (int i = 0; i < 4; ++i) b[i] = Bs[o][tx * 4 + i];
            #pragma unroll
            for (int i = 0; i < 4; ++i)
                #pragma unroll
                for (int jj = 0; jj < 4; ++jj) acc[i][jj] += a[i] * b[jj];
        }
    }
    int ty = tid >> 4, tx = tid & 15;
    #pragma unroll
    for (int i = 0; i < 4; ++i)
        #pragma unroll
        for (int jj = 0; jj < 4; ++jj) {
            int j = j0 + ty * 4 + i, k = k0 + tx * 4 + jj;
            float v = acc[i][jj] + Whh[j * 1024 + k];
            f16 h = (f16)v;
            Bt_hi[j * 1024 + k] = h;
            Bt_lo[j * 1024 + k] = (f16)(v - (float)h);
        }
}

// ---------------- rollout helpers ----------------

// Coherent (cache-bypassing, placement-safe) 16B load: plain pipelined load
// with sc0 sc1 (read from the device coherence point).
__device__ __forceinline__ void ld_sc16(f16x8& d, const f16* p) {
    asm volatile("global_load_dwordx4 %0, %1, off sc0 sc1"
                 : "=&v"(d) : "v"(p) : "memory");
}

// Packed dual-counter wait: low32 = h-arrivals, high32 = all-arrivals.
__device__ __forceinline__ void wait2(u64* cnt, unsigned lo, unsigned hi, bool& gaveup) {
    if (threadIdx.x == 0 && !gaveup) {
        int it = 0;
        for (;;) {
            u64 v = __hip_atomic_load(cnt, __ATOMIC_RELAXED, __HIP_MEMORY_SCOPE_AGENT);
            if ((unsigned)v >= lo && (unsigned)(v >> 32) >= hi) break;
            __builtin_amdgcn_s_sleep(2);
            if (++it > (1 << 21)) { gaveup = true; break; }
        }
    }
    __syncthreads();
}

// One K-split GEMM step: wave w covers k in [w*128, w*128+128).
// A-op = W (hi from swizzled LDS, lo from L2), B-op = h (hi/lo via sc0sc1).
// acc[ct][rt]: D row-block = W-col c = ct*16 + (lane>>4)*4 + reg,
//              D col       = h-row r = rt*16 + (lane&15).
__device__ __forceinline__ void do_gemm(const f16* ph, const f16* plo,
                                        const f16* BsT, const f16* wlo0,
                                        size_t hoff0, int l15, int kq, int w,
                                        f32x4 acc[4][2]) {
    f16x8 hf00, hf01, hf02, hf03, hf10, hf11, hf12, hf13;
    f16x8 lf00, lf01, lf02, lf03, lf10, lf11, lf12, lf13;
    ld_sc16(hf00, ph + hoff0);            ld_sc16(lf00, plo + hoff0);
    ld_sc16(hf01, ph + hoff0 + 32);       ld_sc16(lf01, plo + hoff0 + 32);
    ld_sc16(hf02, ph + hoff0 + 64);       ld_sc16(lf02, plo + hoff0 + 64);
    ld_sc16(hf03, ph + hoff0 + 96);       ld_sc16(lf03, plo + hoff0 + 96);
    ld_sc16(hf10, ph + hoff0 + 16384);    ld_sc16(lf10, plo + hoff0 + 16384);
    ld_sc16(hf11, ph + hoff0 + 16416);    ld_sc16(lf11, plo + hoff0 + 16416);
    ld_sc16(hf12, ph + hoff0 + 16448);    ld_sc16(lf12, plo + hoff0 + 16448);
    ld_sc16(hf13, ph + hoff0 + 16480);    ld_sc16(lf13, plo + hoff0 + 16480);
    const f16x8 hf[2][2][4] = {{{hf00, hf01, hf02, hf03}, {lf00, lf01, lf02, lf03}},
                               {{hf10, hf11, hf12, hf13}, {lf10, lf11, lf12, lf13}}};
    const int swz = (l15 & 7) << 4;
    const int kb = (w * 128 + kq * 8) * 2;
    #pragma unroll
    for (int ct = 0; ct < 4; ++ct) {
        f16x8 wh[4], wl[4];
        #pragma unroll
        for (int kk = 0; kk < 4; ++kk) {
            int byte = ((ct * 16 + l15) * 2048 + kb + kk * 64) ^ swz;
            wh[kk] = *(const f16x8*)((const char*)BsT + byte);
            wl[kk] = *(const f16x8*)(wlo0 + (size_t)ct * 16384 + kk * 32);
        }
        if (ct == 0) {
            asm volatile("s_waitcnt vmcnt(0)" ::: "memory");
            __builtin_amdgcn_sched_barrier(0);
        }
        #pragma unroll
        for (int rt = 0; rt < 2; ++rt)
            #pragma unroll
            for (int kk = 0; kk < 4; ++kk) {
                acc[ct][rt] = MFMA16(wh[kk], hf[rt][0][kk], acc[ct][rt], 0, 0, 0);
                acc[ct][rt] = MFMA16(wh[kk], hf[rt][1][kk], acc[ct][rt], 0, 0, 0);
                acc[ct][rt] = MFMA16(wl[kk], hf[rt][0][kk], acc[ct][rt], 0, 0, 0);
            }
    }
}

// Cross-wave reduction: callers zero Red before their gemm; this does
// barrier -> ds_add_f32 partials -> barrier -> per-thread f32x4 readout.
__device__ __forceinline__ f32x4 reduce_read(float* Red, const f32x4 acc[4][2],
                                             int l15, int kq, int fr, int fc) {
    __syncthreads();
    #pragma unroll
    for (int ct = 0; ct < 4; ++ct)
        #pragma unroll
        for (int rt = 0; rt < 2; ++rt)
            #pragma unroll
            for (int p = 0; p < 4; ++p) {
                int r = rt * 16 + l15, c = ct * 16 + kq * 4 + p;
                atomicAdd(&Red[(r * 64 + c) ^ ((r & 7) << 2)], acc[ct][rt][p]);
            }
    __syncthreads();
    return *(const f32x4*)&Red[(fr * 64 + fc) ^ ((fr & 7) << 2)];
}

__device__ __forceinline__ void store_h4(f16* ph, f16* pl, size_t off, f32x4 v) {
    u64 whi = 0, wlo = 0;
    #pragma unroll
    for (int j = 0; j < 4; ++j) {
        float t = v[j];
        f16 th = (f16)t;
        f16 tl = (f16)(t - (float)th);
        whi |= (u64)__builtin_bit_cast(u16, th) << (16 * j);
        wlo |= (u64)__builtin_bit_cast(u16, tl) << (16 * j);
    }
    __hip_atomic_store((u64*)(ph + off), whi, __ATOMIC_RELAXED, __HIP_MEMORY_SCOPE_AGENT);
    __hip_atomic_store((u64*)(pl + off), wlo, __ATOMIC_RELAXED, __HIP_MEMORY_SCOPE_AGENT);
}

// ---------------- persistent rollout ----------------

__global__ __launch_bounds__(512, 1) void rollout(
    const f16* __restrict__ x0_hi, const f16* __restrict__ x0_lo,
    const f16* __restrict__ Wih_hi, const f16* __restrict__ Wih_lo,
    const f16* __restrict__ Bt_hi, const f16* __restrict__ Bt_lo,
    const float* __restrict__ b1, const float* __restrict__ bcmb,
    const float* __restrict__ bfc,
    f16* hh0, f16* hl0, f16* hh1, f16* hl1, f16* hh2, f16* hl2,
    float* __restrict__ traj, unsigned* __restrict__ syncarea) {
    __shared__ f16 Bs[64 * 1024];   // 128 KB W_hi slice, swizzled
    __shared__ float Red[32 * 64];  // 8 KB reduction buffer, swizzled

    const int wg = blockIdx.x;
    const int g = wg & 7;    // row group (pure index partition)
    const int cg = wg >> 3;  // col group 0..19
    const int tid = threadIdx.x;
    const int lane = tid & 63;
    const int w = tid >> 6;  // wave 0..7 = K-slice owner
    const int l15 = lane & 15;
    const int kq = lane >> 4;  // 0..3
    const bool is_h = (cg < 16);
    const int colbase = is_h ? cg * 64 : 1024 + (cg - 16) * 64;
    const int fr = tid >> 4;         // final-phase row 0..31
    const int fc = (tid & 15) * 4;   // final-phase col base

    u64* cnt = (u64*)(syncarea + g * 64);
    const u64 addv = is_h ? 0x100000001ull : 0x100000000ull;
    bool gaveup = false;

    // stage W_hi slice to LDS (XOR-swizzled)
    {
        const char* gsrc = (const char*)(Bt_hi + (size_t)colbase * 1024);
        char* bs = (char*)Bs;
        #pragma unroll
        for (int i = 0; i < 16; ++i) {
            int f = (tid + i * 512) * 16;
            int c = f >> 11;
            f16x8 v = *(const f16x8*)(gsrc + f);
            *(f16x8*)(bs + (f ^ ((c & 7) << 4))) = v;
        }
    }

    f32x4 biasv;
    {
        const float* bp = is_h ? (bcmb + colbase + fc) : (bfc + colbase - 1024 + fc);
        biasv = (f32x4){bp[0], bp[1], bp[2], bp[3]};
    }
    const size_t hoff0 = (size_t)(g * 32 + l15) * 1024 + w * 128 + kq * 8;
    const f16* wlo0 = Bt_lo + (size_t)(colbase + l15) * 1024 + w * 128 + kq * 8;
    const size_t hwoff = (size_t)(g * 32 + fr) * 1024 + colbase + fc;

    // ---- step 1: h_1 = tanh(x0 @ Wih^T + b1) -> buf1 (h-WGs) ----
    if (is_h) {
        *(f32x4*)&Red[tid * 4] = (f32x4){0.f, 0.f, 0.f, 0.f};
        f32x4 acc[4][2] = {};
        const int k1 = w * 32 + kq * 8;  // K=256 split: 32 per wave
        #pragma unroll
        for (int ct = 0; ct < 4; ++ct) {
            f16x8 wh = *(const f16x8*)(Wih_hi + (size_t)(colbase + ct * 16 + l15) * 256 + k1);
            f16x8 wl = *(const f16x8*)(Wih_lo + (size_t)(colbase + ct * 16 + l15) * 256 + k1);
            #pragma unroll
            for (int rt = 0; rt < 2; ++rt) {
                f16x8 xh = *(const f16x8*)(x0_hi + (size_t)(g * 32 + rt * 16 + l15) * 256 + k1);
                f16x8 xl = *(const f16x8*)(x0_lo + (size_t)(g * 32 + rt * 16 + l15) * 256 + k1);
                acc[ct][rt] = MFMA16(wh, xh, acc[ct][rt], 0, 0, 0);
                acc[ct][rt] = MFMA16(wh, xl, acc[ct][rt], 0, 0, 0);
                acc[ct][rt] = MFMA16(wl, xh, acc[ct][rt], 0, 0, 0);
            }
        }
        f32x4 v = reduce_read(Red, acc, l15, kq, fr, fc);
        const float* bp = b1 + colbase + fc;
        f32x4 tv;
        #pragma unroll
        for (int j = 0; j < 4; ++j) tv[j] = tanhf(v[j] + bp[j]);
        store_h4(hh1, hl1, hwoff, tv);
    }
    __syncthreads();  // drain stores before arrive
    if (tid == 0) __hip_atomic_fetch_add(cnt, addv, __ATOMIC_RELAXED, __HIP_MEMORY_SCOPE_AGENT);

    // ---- main loop: step t computes h_t (h-WGs) and y_{t-1} (y-WGs) ----
    // 3-buffer rotation: read pA (h_{t-1}), write pB (h_t), spare pC.
    f16 *pAh = hh1, *pAl = hl1, *pBh = hh2, *pBl = hl2, *pCh = hh0, *pCl = hl0;
    for (int t = 2; t <= 511; ++t) {
        wait2(cnt, 16u * (t - 1), 20u * (t - 2), gaveup);
        *(f32x4*)&Red[tid * 4] = (f32x4){0.f, 0.f, 0.f, 0.f};
        f32x4 acc[4][2] = {};
        do_gemm(pAh, pAl, Bs, wlo0, hoff0, l15, kq, w, acc);
        f32x4 v = reduce_read(Red, acc, l15, kq, fr, fc);
        v += biasv;
        if (is_h) {
            f32x4 tv;
            #pragma unroll
            for (int j = 0; j < 4; ++j) tv[j] = tanhf(v[j]);
            store_h4(pBh, pBl, hwoff, tv);
        } else {
            *(f32x4*)(traj + (size_t)(t - 1) * 65536 + (size_t)(g * 32 + fr) * 256 +
                      (colbase - 1024) + fc) = v;
        }
        __syncthreads();  // drain stores before arrive
        if (tid == 0) __hip_atomic_fetch_add(cnt, addv, __ATOMIC_RELAXED, __HIP_MEMORY_SCOPE_AGENT);
        // rotate: next read = just-written; next write = spare
        f16 *th_ = pAh, *tl_ = pAl;
        pAh = pBh; pAl = pBl;
        pBh = pCh; pBl = pCl;
        pCh = th_; pCl = tl_;
    }

    // ---- epilogue: y_511 from h_511 (pA after final rotation) ----
    if (!is_h) {
        wait2(cnt, 16u * 511, 20u * 510, gaveup);
        *(f32x4*)&Red[tid * 4] = (f32x4){0.f, 0.f, 0.f, 0.f};
        f32x4 acc[4][2] = {};
        do_gemm(pAh, pAl, Bs, wlo0, hoff0, l15, kq, w, acc);
        f32x4 v = reduce_read(Red, acc, l15, kq, fr, fc);
        v += biasv;
        *(f32x4*)(traj + (size_t)511 * 65536 + (size_t)(g * 32 + fr) * 256 +
                  (colbase - 1024) + fc) = v;
    }
}

// ---------------- launch ----------------

extern "C" void kernel_launch(void* const* d_in, const int* in_sizes, int n_in,
                              void* d_out, int out_size, void* d_ws, size_t ws_size,
                              hipStream_t stream) {
    const float* x0 = (const float*)d_in[0];
    const float* Wih = (const float*)d_in[1];
    const float* bih = (const float*)d_in[2];
    const float* Whh = (const float*)d_in[3];
    const float* bhh = (const float*)d_in[4];
    const float* Wfc = (const float*)d_in[5];
    const float* bfc = (const float*)d_in[6];
    float* traj = (float*)d_out;  // [512][256][256]

    char* w = (char*)d_ws;
    size_t off = 0;
    f16* Bt_hi = (f16*)(w + off); off += 1280u * 1024 * 2;
    f16* Bt_lo = (f16*)(w + off); off += 1280u * 1024 * 2;
    f16* Wih_hi = (f16*)(w + off); off += 1024u * 256 * 2;
    f16* Wih_lo = (f16*)(w + off); off += 1024u * 256 * 2;
    f16* x0_hi = (f16*)(w + off); off += 256u * 256 * 2;
    f16* x0_lo = (f16*)(w + off); off += 256u * 256 * 2;
    f16* hh0 = (f16*)(w + off); off += 256u * 1024 * 2;
    f16* hl0 = (f16*)(w + off); off += 256u * 1024 * 2;
    f16* hh1 = (f16*)(w + off); off += 256u * 1024 * 2;
    f16* hl1 = (f16*)(w + off); off += 256u * 1024 * 2;
    f16* hh2 = (f16*)(w + off); off += 256u * 1024 * 2;
    f16* hl2 = (f16*)(w + off); off += 256u * 1024 * 2;
    float* b1 = (float*)(w + off); off += 4096;
    float* bcmb = (float*)(w + off); off += 4096;
    unsigned* syncarea = (unsigned*)(w + off); off += 4096;

    prep_copy_x0<<<dim3(256), dim3(256), 0, stream>>>(x0, traj, x0_hi, x0_lo, syncarea);
    prep_cast2<<<dim3(1024), dim3(256), 0, stream>>>(Wih, Wih_hi, Wih_lo);
    prep_bias<<<dim3(16), dim3(256), 0, stream>>>(bih, bhh, bfc, Wih, b1, bcmb);
    prep_cast2<<<dim3(1024), dim3(256), 0, stream>>>(Wfc, Bt_hi + 1024 * 1024,
                                                     Bt_lo + 1024 * 1024);
    prep_wcmb<<<dim3(16, 16), dim3(256), 0, stream>>>(Wih, Wfc, Whh, Bt_hi, Bt_lo);

    // persistent rollout: 160 WGs x 512 threads, 1 WG/CU (136 KB LDS), all
    // cross-WG h traffic via coherence-point (sc0 sc1 / agent) ops ->
    // placement-independent; barriers do zero cache maintenance.
    rollout<<<dim3(NWG), dim3(512), 0, stream>>>(
        x0_hi, x0_lo, Wih_hi, Wih_lo, Bt_hi, Bt_lo, b1, bcmb, bfc,
        hh0, hl0, hh1, hl1, hh2, hl2, traj, syncarea);
}